// Round 1
// baseline (226.319 us; speedup 1.0000x reference)
//
#include <hip/hip_runtime.h>

#define EPS 1e-7f

typedef float fx4 __attribute__((ext_vector_type(4)));

// Fused single-pass kernel.
//
// Layout: idx = b*C + c, C = 1024 (power of two). Grid-stride with
// stride S = gridDim*blockDim chosen as a multiple of C, so each
// thread's channel c = idx & (C-1) is INVARIANT across its UNROLL
// iterations -> per-channel boost params are computed once per thread
// (2 sqrt + 1 div, trivially hidden under 64 B of HBM traffic) and
// amortized over UNROLL streamed 4-vectors.
//
// Per-element math (identical arithmetic to the verified 2-kernel
// version, absmax 0.0156 pass):
//   B00   = 1 + (g-1)*nn          (nn = n.n, mirrors ref's nK2[0][0])
//   out0  = B00*x0 - g*mag*(n.v)
//   s     = (g-1)*(n.v) - g*mag*x0
//   out_i = x_i + n_i * s
__global__ __launch_bounds__(256) void lorentz_fused_kernel(
    const fx4* __restrict__ T, const float* __restrict__ Bo,
    fx4* __restrict__ out, int total, int cmask)
{
    const int S = gridDim.x * blockDim.x;          // multiple of C by launch config
    const int idx = blockIdx.x * blockDim.x + threadIdx.x;
    const int c = idx & cmask;

    // --- per-channel params (exactly mirrors previous params kernel) ---
    float b0 = Bo[c * 3 + 0];
    float b1 = Bo[c * 3 + 1];
    float b2 = Bo[c * 3 + 2];
    float mag = sqrtf(b0 * b0 + b1 * b1 + b2 * b2);
    mag = fminf(fmaxf(mag, EPS), 1.0f - EPS);
    float inv = 1.0f / mag;
    float n0 = b0 * inv, n1 = b1 * inv, n2 = b2 * inv;
    float g = 1.0f / sqrtf(1.0f - mag * mag);
    float nn = n0 * n0 + n1 * n1 + n2 * n2;        // mirrors ref's nK2[0][0]
    float B00 = 1.0f + (g - 1.0f) * nn;
    float gm = g * mag;
    float gm1 = g - 1.0f;

    // --- stream UNROLL fx4 elements: issue all loads, then compute+store ---
    fx4 x0v, x1v, x2v, x3v;
    const int i0 = idx;
    const int i1 = idx + S;
    const int i2 = idx + 2 * S;
    const int i3 = idx + 3 * S;
    if (i0 < total) x0v = __builtin_nontemporal_load(&T[i0]);
    if (i1 < total) x1v = __builtin_nontemporal_load(&T[i1]);
    if (i2 < total) x2v = __builtin_nontemporal_load(&T[i2]);
    if (i3 < total) x3v = __builtin_nontemporal_load(&T[i3]);

#define APPLY_STORE(xv, ii)                                        \
    do {                                                           \
        if ((ii) < total) {                                        \
            fx4 v = (xv);                                          \
            float d = n0 * v.y + n1 * v.z + n2 * v.w;              \
            float s = gm1 * d - gm * v.x;                          \
            fx4 o = {B00 * v.x - gm * d,                           \
                     v.y + n0 * s,                                 \
                     v.z + n1 * s,                                 \
                     v.w + n2 * s};                                \
            __builtin_nontemporal_store(o, &out[ii]);              \
        }                                                          \
    } while (0)

    APPLY_STORE(x0v, i0);
    APPLY_STORE(x1v, i1);
    APPLY_STORE(x2v, i2);
    APPLY_STORE(x3v, i3);
#undef APPLY_STORE
}

extern "C" void kernel_launch(void* const* d_in, const int* in_sizes, int n_in,
                              void* d_out, int out_size, void* d_ws, size_t ws_size,
                              hipStream_t stream)
{
    const fx4* T  = (const fx4*)d_in[0];
    const float* Bo = (const float*)d_in[1];
    fx4* out = (fx4*)d_out;

    const int C = in_sizes[1] / 3;                 // 1024 channels (power of 2)
    const int total = out_size / 4;                // number of 4-vectors (8192*1024)

    const int UNROLL = 4;
    const int BLOCK = 256;
    int blocks = (total + BLOCK * UNROLL - 1) / (BLOCK * UNROLL);
    // Ensure stride = blocks*BLOCK is a multiple of C so each thread's
    // channel is invariant across its unrolled iterations.
    const int align = (C + BLOCK - 1) / BLOCK;     // C/256 = 4
    blocks = ((blocks + align - 1) / align) * align;

    lorentz_fused_kernel<<<blocks, BLOCK, 0, stream>>>(T, Bo, out, total, C - 1);
}

// Round 2
// 222.658 us; speedup vs baseline: 1.0164x; 1.0164x over previous
//
#include <hip/hip_runtime.h>

#define EPS 1e-7f

typedef float fx4 __attribute__((ext_vector_type(4)));

// Two-kernel structure: tiny params kernel (4K threads) + streaming apply.
// This is the best-measured variant (221.4 µs R0, 222.2 µs prior session).
// The fused single-kernel variant measured 226.3 µs (R1) — the params
// recompute across 2M threads + strided Bo gather cost more than the
// launch/dependency edge it removed.

// Params per channel: pa = {n0, n1, n2, B00}, pb = {g*mag, g-1, 0, 0}
__global__ __launch_bounds__(256) void lorentz_params_kernel(
    const float* __restrict__ Bo, fx4* __restrict__ P, int C)
{
    int c = blockIdx.x * blockDim.x + threadIdx.x;
    if (c >= C) return;
    float b0 = Bo[c * 3 + 0];
    float b1 = Bo[c * 3 + 1];
    float b2 = Bo[c * 3 + 2];
    float mag = sqrtf(b0 * b0 + b1 * b1 + b2 * b2);
    mag = fminf(fmaxf(mag, EPS), 1.0f - EPS);
    float inv = 1.0f / mag;
    float n0 = b0 * inv, n1 = b1 * inv, n2 = b2 * inv;
    float g = 1.0f / sqrtf(1.0f - mag * mag);
    float nn = n0 * n0 + n1 * n1 + n2 * n2;   // exactly mirrors ref's nK2[0][0]
    float B00 = 1.0f + (g - 1.0f) * nn;
    fx4 pa = {n0, n1, n2, B00};
    fx4 pb = {g * mag, g - 1.0f, 0.0f, 0.0f};
    P[c * 2 + 0] = pa;
    P[c * 2 + 1] = pb;
}

// One thread per (b,c) 4-vector. idx = b*C + c, C = 1024 (power of 2).
__global__ __launch_bounds__(256) void lorentz_apply_kernel(
    const fx4* __restrict__ T, const fx4* __restrict__ P,
    fx4* __restrict__ out, int total)
{
    int idx = blockIdx.x * blockDim.x + threadIdx.x;
    if (idx >= total) return;
    int c = idx & 1023;

    fx4 x  = __builtin_nontemporal_load(&T[idx]);
    fx4 pa = P[c * 2 + 0];   // cached (32 KB table, L1/L2 resident)
    fx4 pb = P[c * 2 + 1];

    float d  = pa.x * x.y + pa.y * x.z + pa.z * x.w;   // n . v
    float o0 = pa.w * x.x - pb.x * d;                  // B00*x0 - gm*d
    float s  = pb.y * d - pb.x * x.x;                  // gm1*d - gm*x0
    fx4 o = {o0,
             x.y + pa.x * s,
             x.z + pa.y * s,
             x.w + pa.z * s};
    __builtin_nontemporal_store(o, &out[idx]);
}

extern "C" void kernel_launch(void* const* d_in, const int* in_sizes, int n_in,
                              void* d_out, int out_size, void* d_ws, size_t ws_size,
                              hipStream_t stream)
{
    const fx4* T  = (const fx4*)d_in[0];
    const float* Bo = (const float*)d_in[1];
    fx4* out = (fx4*)d_out;
    fx4* P   = (fx4*)d_ws;

    int C = in_sizes[1] / 3;                 // 1024 channels
    int total = out_size / 4;                // number of 4-vectors (8192*1024)

    lorentz_params_kernel<<<(C + 255) / 256, 256, 0, stream>>>(Bo, P, C);
    lorentz_apply_kernel<<<(total + 255) / 256, 256, 0, stream>>>(T, P, out, total);
}